// Round 1
// baseline (1263.161 us; speedup 1.0000x reference)
//
#include <hip/hip_runtime.h>
#include <math.h>

typedef unsigned int u32;
typedef unsigned long long u64;

#define A_TOTAL 49152
#define NKEEP 2000
#define NTOPK 300
#define CANDN 2048
#define SORTN 4096

// ws layout (bytes)
#define OFF_X      0u            // 512*4096 f32  (8388608)
#define OFF_OX     8388608u      // 12*4096 f32
#define OFF_AX     8585216u      // 48*4096 f32
#define OFF_BOXES  9371648u      // 49152*4 f32
#define OFF_SCORES 10158080u     // 49152 f32
#define OFF_HIST   10354688u     // 65536 u32
#define OFF_KEYS   10616832u     // 4096 u64
#define OFF_CAND5  10649600u     // 2048*5 f32
#define OFF_MASK   10690560u     // 2048*32 u64
#define OFF_MISC   11214848u     // [0]=counter,[1]=B1 ; +64B: suppws u64[32]

__global__ __launch_bounds__(256) void k_init(u32* __restrict__ hist, u64* __restrict__ keys,
                                              u32* __restrict__ misc, float* __restrict__ out) {
    int t = blockIdx.x * 256 + threadIdx.x;
    if (t < 65536) hist[t] = 0u;
    if (t < SORTN) keys[t] = 0ull;
    if (t < NTOPK * 5) out[t] = 0.f;
    if (t == 0) misc[0] = 0u;
}

// conv1: 3x3, 1024->512, pad 1, ReLU. f32 chunk accum (144 terms) + f64 across chunks.
// block: 256 thr = 32 co-pairs x 8 pixel-rows; tile: 64 c_out x 8x8 pixels.
__global__ __launch_bounds__(256) void k_conv1(const float* __restrict__ fx, const float* __restrict__ w1,
                                               const float* __restrict__ b1, float* __restrict__ xout) {
    __shared__ float sfx[16][10][10];
    __shared__ float swT[16][9][64];
    const int tid = threadIdx.x;
    const int co0 = blockIdx.x * 64;
    const int tile = blockIdx.y;
    const int ty0 = (tile >> 3) << 3;
    const int tx0 = (tile & 7) << 3;
    const int tx = tid & 31;   // co pair
    const int ty = tid >> 5;   // pixel row 0..7

    double accD[2][8];
#pragma unroll
    for (int c = 0; c < 2; c++)
#pragma unroll
        for (int p = 0; p < 8; p++) accD[c][p] = 0.0;

    for (int ci0 = 0; ci0 < 1024; ci0 += 16) {
        __syncthreads();
        // stage fx [16][10][10] with zero halo
        for (int e = tid; e < 1600; e += 256) {
            int ci = e / 100, r = e - ci * 100;
            int iy = r / 10, ix = r - iy * 10;
            int gy = ty0 + iy - 1, gx = tx0 + ix - 1;
            float v = 0.f;
            if (gy >= 0 && gy < 64 && gx >= 0 && gx < 64)
                v = fx[(size_t)(ci0 + ci) * 4096 + gy * 64 + gx];
            sfx[ci][iy][ix] = v;
        }
        // stage weights transposed: swT[ci][tap][co]
        for (int e = tid; e < 9216; e += 256) {
            int co = e / 144, r = e - co * 144;   // r = ci*9+tap, contiguous in w1
            int ci = r / 9, tap = r - ci * 9;
            swT[ci][tap][co] = w1[(size_t)(co0 + co) * 9216 + (size_t)(ci0 + ci) * 9 + tap];
        }
        __syncthreads();

        float acc[2][8];
#pragma unroll
        for (int c = 0; c < 2; c++)
#pragma unroll
            for (int p = 0; p < 8; p++) acc[c][p] = 0.f;

#pragma unroll 1
        for (int ci = 0; ci < 16; ci++) {
#pragma unroll
            for (int dy = 0; dy < 3; dy++) {
                float r[10];
#pragma unroll
                for (int j = 0; j < 10; j++) r[j] = sfx[ci][ty + dy][j];
#pragma unroll
                for (int dx = 0; dx < 3; dx++) {
                    float2 wv = *(const float2*)&swT[ci][dy * 3 + dx][tx * 2];
#pragma unroll
                    for (int p = 0; p < 8; p++) {
                        acc[0][p] += r[p + dx] * wv.x;
                        acc[1][p] += r[p + dx] * wv.y;
                    }
                }
            }
        }
#pragma unroll
        for (int c = 0; c < 2; c++)
#pragma unroll
            for (int p = 0; p < 8; p++) accD[c][p] += (double)acc[c][p];
    }

#pragma unroll
    for (int c = 0; c < 2; c++) {
        int co = co0 + tx * 2 + c;
        double bb = (double)b1[co];
#pragma unroll
        for (int p = 0; p < 8; p++) {
            float v = (float)(accD[c][p] + bb);
            xout[(size_t)co * 4096 + (ty0 + ty) * 64 + tx0 + p] = fmaxf(v, 0.f);
        }
    }
}

// 1x1 convs: o in [0,60): o<12 -> ox, else ax3.  f64 accumulate.
__global__ __launch_bounds__(256) void k_conv23(const float* __restrict__ x,
                                                const float* __restrict__ w2, const float* __restrict__ b2,
                                                const float* __restrict__ w3, const float* __restrict__ b3,
                                                float* __restrict__ ox, float* __restrict__ ax3) {
    int t = blockIdx.x * 256 + threadIdx.x;
    int px = t & 4095;
    int o = t >> 12;
    if (o >= 60) return;
    const float* w;
    float bias;
    float* dst;
    if (o < 12) { w = w2 + o * 512; bias = b2[o]; dst = ox + (size_t)o * 4096; }
    else        { w = w3 + (size_t)(o - 12) * 512; bias = b3[o - 12]; dst = ax3 + (size_t)(o - 12) * 4096; }
    double acc = 0.0;
#pragma unroll 8
    for (int ci = 0; ci < 512; ci++)
        acc = fma((double)x[(size_t)ci * 4096 + px], (double)w[ci], acc);
    dst[px] = (float)(acc + (double)bias);
}

// decode: scores (f64 sigmoid -> f32), boxes (f64 decode -> f32, clipped), histogram of score bits>>16
__global__ __launch_bounds__(256) void k_boxes(const float* __restrict__ ox, const float* __restrict__ ax3,
                                               const int* __restrict__ imh, const int* __restrict__ imw,
                                               float* __restrict__ boxes, float* __restrict__ scores,
                                               u32* __restrict__ hist) {
    int idx = blockIdx.x * 256 + threadIdx.x;
    if (idx >= A_TOTAL) return;
    int px = idx / 12, a = idx - px * 12;
    float o = ox[(size_t)a * 4096 + px];
    float s = (float)(1.0 / (1.0 + exp(-(double)o)));
    scores[idx] = s;
    atomicAdd(&hist[__float_as_uint(s) >> 16], 1u);

    int py = px >> 6, pxx = px & 63;
    double cx = pxx * 16.0 + 8.0, cy = py * 16.0 + 8.0;
    int si = a / 3, ri = a - si * 3;
    double scale = (double)(32 << si);
    double ratio = 0.5 * (double)(1 << ri);
    double sq = sqrt(ratio);
    double aw = scale * sq, ah = scale / sq;
    float d0 = ax3[(size_t)(a * 4 + 0) * 4096 + px];
    float d1 = ax3[(size_t)(a * 4 + 1) * 4096 + px];
    float d2 = ax3[(size_t)(a * 4 + 2) * 4096 + px];
    float d3 = ax3[(size_t)(a * 4 + 3) * 4096 + px];
    double xc = cx + (double)d0 * aw;
    double yc = cy + (double)d1 * ah;
    double wv = aw * exp((double)d2);
    double hv = ah * exp((double)d3);
    float W = (float)imw[0], H = (float)imh[0];
    float x1 = fminf(fmaxf((float)(xc - wv * 0.5), 0.f), W);
    float x2 = fminf(fmaxf((float)(xc + wv * 0.5), 0.f), W);
    float y1 = fminf(fmaxf((float)(yc - hv * 0.5), 0.f), H);
    float y2 = fminf(fmaxf((float)(yc + hv * 0.5), 0.f), H);
    boxes[(size_t)idx * 4 + 0] = x1;
    boxes[(size_t)idx * 4 + 1] = y1;
    boxes[(size_t)idx * 4 + 2] = x2;
    boxes[(size_t)idx * 4 + 3] = y2;
}

// find boundary bin B1 so that count(bins >= B1) >= 2000, count(bins > B1) < 2000
__global__ __launch_bounds__(256) void k_scanhist(const u32* __restrict__ hist, u32* __restrict__ misc) {
    __shared__ u32 csum[256];
    __shared__ u32 cb[256];
    __shared__ int s_cidx;
    __shared__ u32 s_cacc;
    int t = threadIdx.x;
    u32 sum = 0;
    const uint4* h4 = (const uint4*)(hist + t * 256);
    for (int j = 0; j < 64; j++) { uint4 v = h4[j]; sum += v.x + v.y + v.z + v.w; }
    csum[t] = sum;
    __syncthreads();
    if (t == 0) {
        u32 acc = 0;
        int c = 255;
        for (; c > 0; c--) {
            if (acc + csum[c] >= NKEEP) break;
            acc += csum[c];
        }
        s_cidx = c;
        s_cacc = acc;
    }
    __syncthreads();
    cb[t] = hist[s_cidx * 256 + t];
    __syncthreads();
    if (t == 0) {
        u32 acc = s_cacc;
        int b = 255;
        for (; b > 0; b--) {
            acc += cb[b];
            if (acc >= NKEEP) break;
        }
        misc[1] = (u32)(s_cidx * 256 + b);
    }
}

__global__ __launch_bounds__(256) void k_compact(const float* __restrict__ scores, u32* __restrict__ misc,
                                                 u64* __restrict__ keys) {
    int idx = blockIdx.x * 256 + threadIdx.x;
    if (idx >= A_TOTAL) return;
    u32 bits = __float_as_uint(scores[idx]);
    if ((bits >> 16) >= misc[1]) {
        u32 slot = atomicAdd(&misc[0], 1u);
        if (slot < SORTN) keys[slot] = ((u64)bits << 32) | (u64)(~(u32)idx);
    }
}

// bitonic sort 4096 keys DESC (score desc, index asc), then gather cand rows + init suppression words
__global__ __launch_bounds__(1024) void k_sort(const u64* __restrict__ keys, const float* __restrict__ boxes,
                                               float* __restrict__ cand5, u64* __restrict__ suppws) {
    __shared__ u64 lk[SORTN];
    int t = threadIdx.x;
#pragma unroll
    for (int r = 0; r < 4; r++) lk[r * 1024 + t] = keys[r * 1024 + t];
    for (int kk = 2; kk <= SORTN; kk <<= 1) {
        for (int jj = kk >> 1; jj > 0; jj >>= 1) {
            __syncthreads();
#pragma unroll
            for (int rep = 0; rep < 4; rep++) {
                int i = rep * 1024 + t;
                int ixj = i ^ jj;
                if (ixj > i) {
                    u64 a = lk[i], b = lk[ixj];
                    bool sw = ((i & kk) == 0) ? (a < b) : (a > b);  // descending overall
                    if (sw) { lk[i] = b; lk[ixj] = a; }
                }
            }
        }
    }
    __syncthreads();
#pragma unroll
    for (int rep = 0; rep < 2; rep++) {
        int i = rep * 1024 + t;
        bool suppb = true;
        float c0 = 0.f, c1 = 0.f, c2 = 0.f, c3 = 0.f, cs = 0.f;
        if (i < NKEEP) {
            u64 key = lk[i];
            u32 idx = ~(u32)(key & 0xFFFFFFFFull);
            cs = __uint_as_float((u32)(key >> 32));
            c0 = boxes[(size_t)idx * 4 + 0];
            c1 = boxes[(size_t)idx * 4 + 1];
            c2 = boxes[(size_t)idx * 4 + 2];
            c3 = boxes[(size_t)idx * 4 + 3];
            bool valid = ((c2 - c0) >= 16.f) && ((c3 - c1) >= 16.f) && (cs >= 0.05f);
            suppb = !valid;
        }
        cand5[i * 5 + 0] = c0;
        cand5[i * 5 + 1] = c1;
        cand5[i * 5 + 2] = c2;
        cand5[i * 5 + 3] = c3;
        cand5[i * 5 + 4] = cs;
        u64 bal = __ballot(suppb ? 1 : 0);
        if ((t & 63) == 0) suppws[i >> 6] = bal;
    }
}

// IoU > 0.7 bitmask, 64x64 tiles
__global__ __launch_bounds__(64) void k_mask(const float* __restrict__ cand5, u64* __restrict__ mask) {
    __shared__ float cb[64][5];
    int t = threadIdx.x;
    int bi = blockIdx.y, bj = blockIdx.x;
    int j = bj * 64 + t;
    {
        float b0 = cand5[j * 5 + 0], b1v = cand5[j * 5 + 1], b2v = cand5[j * 5 + 2], b3v = cand5[j * 5 + 3];
        cb[t][0] = b0; cb[t][1] = b1v; cb[t][2] = b2v; cb[t][3] = b3v;
        cb[t][4] = (b2v - b0) * (b3v - b1v);
    }
    __syncthreads();
    int i = bi * 64 + t;
    float r0 = cand5[i * 5 + 0], r1 = cand5[i * 5 + 1], r2 = cand5[i * 5 + 2], r3 = cand5[i * 5 + 3];
    float ra = (r2 - r0) * (r3 - r1);
    u64 bits = 0ull;
#pragma unroll 4
    for (int c = 0; c < 64; c++) {
        float lx = fmaxf(r0, cb[c][0]);
        float ly = fmaxf(r1, cb[c][1]);
        float rx = fminf(r2, cb[c][2]);
        float ry = fminf(r3, cb[c][3]);
        float w = fmaxf(rx - lx, 0.f);
        float h = fmaxf(ry - ly, 0.f);
        float inter = w * h;
        float iou = inter / fmaxf(ra + cb[c][4] - inter, 1e-6f);
        if (iou > 0.7f) bits |= (1ull << c);
    }
    mask[(size_t)i * 32 + bj] = bits;
}

// single-wave greedy NMS scan with depth-8 prefetch; writes first <=300 kept rows
__global__ __launch_bounds__(64) void k_scan(const u64* __restrict__ mask, const float* __restrict__ cand5,
                                             const u64* __restrict__ suppws, float* __restrict__ out) {
    int lane = threadIdx.x;
    u64 supp = (lane < 32) ? suppws[lane] : 0ull;
    u64 bufA[8], bufB[8];
    float dA[8], dB[8];
#pragma unroll
    for (int k = 0; k < 8; k++) {
        bufA[k] = (lane < 32) ? mask[(size_t)k * 32 + lane] : 0ull;
        dA[k] = (lane < 5) ? cand5[k * 5 + lane] : 0.f;
    }
    int kcount = 0;
    for (int g = 0; g < 256; g++) {
        int base = g * 8;
        if (g < 255) {
            int nb = base + 8;
#pragma unroll
            for (int k = 0; k < 8; k++) {
                bufB[k] = (lane < 32) ? mask[(size_t)(nb + k) * 32 + lane] : 0ull;
                dB[k] = (lane < 5) ? cand5[(nb + k) * 5 + lane] : 0.f;
            }
        }
        int w = g >> 3;
        u64 cur = __shfl(supp, w);
#pragma unroll
        for (int k = 0; k < 8; k++) {
            int i = base + k;
            if (i < NKEEP && !((cur >> (i & 63)) & 1ull)) {
                if (kcount < NTOPK) {
                    if (lane < 5) out[kcount * 5 + lane] = dA[k];
                    kcount++;
                }
                supp |= bufA[k];
                cur |= __shfl(bufA[k], w);
            }
        }
        if (kcount >= NTOPK) return;
#pragma unroll
        for (int k = 0; k < 8; k++) { bufA[k] = bufB[k]; dA[k] = dB[k]; }
    }
}

extern "C" void kernel_launch(void* const* d_in, const int* in_sizes, int n_in,
                              void* d_out, int out_size, void* d_ws, size_t ws_size,
                              hipStream_t stream) {
    (void)in_sizes; (void)n_in; (void)out_size; (void)ws_size;
    const float* fx = (const float*)d_in[0];
    const float* w1 = (const float*)d_in[1];
    const float* b1 = (const float*)d_in[2];
    const float* w2 = (const float*)d_in[3];
    const float* b2 = (const float*)d_in[4];
    const float* w3 = (const float*)d_in[5];
    const float* b3 = (const float*)d_in[6];
    const int* imh = (const int*)d_in[7];
    const int* imw = (const int*)d_in[8];

    char* ws = (char*)d_ws;
    float* x      = (float*)(ws + OFF_X);
    float* ox     = (float*)(ws + OFF_OX);
    float* ax3    = (float*)(ws + OFF_AX);
    float* boxes  = (float*)(ws + OFF_BOXES);
    float* scores = (float*)(ws + OFF_SCORES);
    u32*   hist   = (u32*)(ws + OFF_HIST);
    u64*   keys   = (u64*)(ws + OFF_KEYS);
    float* cand5  = (float*)(ws + OFF_CAND5);
    u64*   mask   = (u64*)(ws + OFF_MASK);
    u32*   misc   = (u32*)(ws + OFF_MISC);
    u64*   suppws = (u64*)(ws + OFF_MISC + 64);
    float* out    = (float*)d_out;

    k_init<<<256, 256, 0, stream>>>(hist, keys, misc, out);
    k_conv1<<<dim3(8, 64), 256, 0, stream>>>(fx, w1, b1, x);
    k_conv23<<<960, 256, 0, stream>>>(x, w2, b2, w3, b3, ox, ax3);
    k_boxes<<<192, 256, 0, stream>>>(ox, ax3, imh, imw, boxes, scores, hist);
    k_scanhist<<<1, 256, 0, stream>>>(hist, misc);
    k_compact<<<192, 256, 0, stream>>>(scores, misc, keys);
    k_sort<<<1, 1024, 0, stream>>>(keys, boxes, cand5, suppws);
    k_mask<<<dim3(32, 32), 64, 0, stream>>>(cand5, mask);
    k_scan<<<1, 64, 0, stream>>>(mask, cand5, suppws, out);
}

// Round 2
// 842.977 us; speedup vs baseline: 1.4985x; 1.4985x over previous
//
#include <hip/hip_runtime.h>
#include <math.h>

typedef unsigned int u32;
typedef unsigned long long u64;

#define A_TOTAL 49152
#define NKEEP 2000
#define NTOPK 300
#define CANDN 2048
#define SORTN 4096

// ws layout (bytes)
#define OFF_X      0u            // 512*4096 f32  (8388608)
#define OFF_OX     8388608u      // 12*4096 f32
#define OFF_AX     8585216u      // 48*4096 f32
#define OFF_BOXES  9371648u      // 49152*4 f32
#define OFF_SCORES 10158080u     // 49152 f32
#define OFF_HIST   10354688u     // 65536 u32
#define OFF_KEYS   10616832u     // 4096 u64
#define OFF_CAND5  10649600u     // 2048*5 f32
#define OFF_MASK   10690560u     // 2048*32 u64
#define OFF_MISC   11214848u     // [0]=counter,[1]=B1 ; +64B: suppws u64[32]

__global__ __launch_bounds__(256) void k_init(u32* __restrict__ hist, u64* __restrict__ keys,
                                              u32* __restrict__ misc, float* __restrict__ out) {
    int t = blockIdx.x * 256 + threadIdx.x;
    if (t < 65536) hist[t] = 0u;
    if (t < SORTN) keys[t] = 0ull;
    if (t < NTOPK * 5) out[t] = 0.f;
    if (t == 0) misc[0] = 0u;
}

// conv1: 3x3, 1024->512, pad 1, ReLU.
// block: 256 thr = 32 co-pairs x 8 pixel-rows; tile: 64 c_out x 8x8 px; ci chunks of 8.
// f32 accum within 8-ci chunk (72 terms) + f64 across chunks (ranking-exact).
// LDS: sfx rows padded to 12 (16B-aligned vector reads); weights padded to stride 66
// (write conflicts 32-way -> 4-way, float2 reads stay 8B-aligned).
// T14: next chunk's global loads issued to regs before the compute barrier.
__global__ __launch_bounds__(256) void k_conv1(const float* __restrict__ fx, const float* __restrict__ w1,
                                               const float* __restrict__ b1, float* __restrict__ xout) {
    __shared__ float sfx[8 * 120];     // [ci][iy(10)][ix(12)]
    __shared__ float swT[72 * 66];     // [ci*9+tap][co padded to 66]
    const int tid = threadIdx.x;
    const int co0 = blockIdx.x * 64;
    const int tile = blockIdx.y;
    const int ty0 = (tile >> 3) << 3;
    const int tx0 = (tile & 7) << 3;
    const int tx = tid & 31;   // co pair
    const int ty = tid >> 5;   // pixel row 0..7

    // --- staging descriptors (chunk-invariant) ---
    int fx_g[4], fx_l[4];
    bool fx_wr[4], fx_ld[4];
#pragma unroll
    for (int j = 0; j < 4; j++) {
        int e = tid + j * 256;
        int ci = e / 120, r = e - ci * 120;
        int iy = r / 12, ix = r - iy * 12;
        int gy = ty0 + iy - 1, gx = tx0 + ix - 1;
        bool wr = (e < 960) && (ix < 10);
        bool ld = wr && (gy >= 0) && (gy < 64) && (gx >= 0) && (gx < 64);
        fx_wr[j] = wr;
        fx_ld[j] = ld;
        fx_g[j] = ci * 4096 + gy * 64 + gx;
        fx_l[j] = wr ? (ci * 120 + iy * 12 + ix) : 0;
    }
    int w_g[18], w_l[18];
#pragma unroll
    for (int j = 0; j < 18; j++) {
        int e = tid + j * 256;             // 18*256 = 4608 = 64co * 8ci * 9tap, all valid
        int co = e / 72, r = e - co * 72;
        int ci = r / 9, tap = r - ci * 9;
        w_g[j] = co * 9216 + ci * 9 + tap; // coalesced: r contiguous in w1 per co
        w_l[j] = (ci * 9 + tap) * 66 + co;
    }

    double accD[2][8];
#pragma unroll
    for (int c = 0; c < 2; c++)
#pragma unroll
        for (int p = 0; p < 8; p++) accD[c][p] = 0.0;

    float pw[18], pfx[4];
    // prefetch chunk 0
    {
        const float* wbase = w1 + (size_t)co0 * 9216;
#pragma unroll
        for (int j = 0; j < 18; j++) pw[j] = wbase[w_g[j]];
#pragma unroll
        for (int j = 0; j < 4; j++) pfx[j] = fx_ld[j] ? fx[fx_g[j]] : 0.f;
    }

#pragma unroll 1
    for (int cc = 0; cc < 128; cc++) {
        __syncthreads();                   // previous compute done; LDS writable
#pragma unroll
        for (int j = 0; j < 18; j++) swT[w_l[j]] = pw[j];
#pragma unroll
        for (int j = 0; j < 4; j++)
            if (fx_wr[j]) sfx[fx_l[j]] = pfx[j];
        if (cc < 127) {                    // issue next chunk's loads; land during compute
            int ci0 = (cc + 1) * 8;
            const float* wbase = w1 + (size_t)co0 * 9216 + (size_t)ci0 * 9;
            const float* fbase = fx + (size_t)ci0 * 4096;
#pragma unroll
            for (int j = 0; j < 18; j++) pw[j] = wbase[w_g[j]];
#pragma unroll
            for (int j = 0; j < 4; j++) pfx[j] = fx_ld[j] ? fbase[fx_g[j]] : 0.f;
        }
        __syncthreads();

        float acc[2][8];
#pragma unroll
        for (int c = 0; c < 2; c++)
#pragma unroll
            for (int p = 0; p < 8; p++) acc[c][p] = 0.f;

#pragma unroll 1
        for (int ci = 0; ci < 8; ci++) {
#pragma unroll
            for (int dy = 0; dy < 3; dy++) {
                const float* row = &sfx[ci * 120 + (ty + dy) * 12];
                float4 ra = *(const float4*)row;
                float4 rb = *(const float4*)(row + 4);
                float2 rc = *(const float2*)(row + 8);
                float r[10] = {ra.x, ra.y, ra.z, ra.w, rb.x, rb.y, rb.z, rb.w, rc.x, rc.y};
#pragma unroll
                for (int dx = 0; dx < 3; dx++) {
                    float2 wv = *(const float2*)&swT[(ci * 9 + dy * 3 + dx) * 66 + tx * 2];
#pragma unroll
                    for (int p = 0; p < 8; p++) {
                        acc[0][p] += r[p + dx] * wv.x;
                        acc[1][p] += r[p + dx] * wv.y;
                    }
                }
            }
        }
#pragma unroll
        for (int c = 0; c < 2; c++)
#pragma unroll
            for (int p = 0; p < 8; p++) accD[c][p] += (double)acc[c][p];
    }

#pragma unroll
    for (int c = 0; c < 2; c++) {
        int co = co0 + tx * 2 + c;
        double bb = (double)b1[co];
#pragma unroll
        for (int p = 0; p < 8; p++) {
            float v = (float)(accD[c][p] + bb);
            xout[(size_t)co * 4096 + (ty0 + ty) * 64 + tx0 + p] = fmaxf(v, 0.f);
        }
    }
}

// 1x1 convs: o in [0,60): o<12 -> ox, else ax3.  f64 accumulate.
__global__ __launch_bounds__(256) void k_conv23(const float* __restrict__ x,
                                                const float* __restrict__ w2, const float* __restrict__ b2,
                                                const float* __restrict__ w3, const float* __restrict__ b3,
                                                float* __restrict__ ox, float* __restrict__ ax3) {
    int t = blockIdx.x * 256 + threadIdx.x;
    int px = t & 4095;
    int o = t >> 12;
    if (o >= 60) return;
    const float* w;
    float bias;
    float* dst;
    if (o < 12) { w = w2 + o * 512; bias = b2[o]; dst = ox + (size_t)o * 4096; }
    else        { w = w3 + (size_t)(o - 12) * 512; bias = b3[o - 12]; dst = ax3 + (size_t)(o - 12) * 4096; }
    double acc = 0.0;
#pragma unroll 8
    for (int ci = 0; ci < 512; ci++)
        acc = fma((double)x[(size_t)ci * 4096 + px], (double)w[ci], acc);
    dst[px] = (float)(acc + (double)bias);
}

// decode: scores (f64 sigmoid -> f32), boxes (f64 decode -> f32, clipped), histogram of score bits>>16
__global__ __launch_bounds__(256) void k_boxes(const float* __restrict__ ox, const float* __restrict__ ax3,
                                               const int* __restrict__ imh, const int* __restrict__ imw,
                                               float* __restrict__ boxes, float* __restrict__ scores,
                                               u32* __restrict__ hist) {
    int idx = blockIdx.x * 256 + threadIdx.x;
    if (idx >= A_TOTAL) return;
    int px = idx / 12, a = idx - px * 12;
    float o = ox[(size_t)a * 4096 + px];
    float s = (float)(1.0 / (1.0 + exp(-(double)o)));
    scores[idx] = s;
    atomicAdd(&hist[__float_as_uint(s) >> 16], 1u);

    int py = px >> 6, pxx = px & 63;
    double cx = pxx * 16.0 + 8.0, cy = py * 16.0 + 8.0;
    int si = a / 3, ri = a - si * 3;
    double scale = (double)(32 << si);
    double ratio = 0.5 * (double)(1 << ri);
    double sq = sqrt(ratio);
    double aw = scale * sq, ah = scale / sq;
    float d0 = ax3[(size_t)(a * 4 + 0) * 4096 + px];
    float d1 = ax3[(size_t)(a * 4 + 1) * 4096 + px];
    float d2 = ax3[(size_t)(a * 4 + 2) * 4096 + px];
    float d3 = ax3[(size_t)(a * 4 + 3) * 4096 + px];
    double xc = cx + (double)d0 * aw;
    double yc = cy + (double)d1 * ah;
    double wv = aw * exp((double)d2);
    double hv = ah * exp((double)d3);
    float W = (float)imw[0], H = (float)imh[0];
    float x1 = fminf(fmaxf((float)(xc - wv * 0.5), 0.f), W);
    float x2 = fminf(fmaxf((float)(xc + wv * 0.5), 0.f), W);
    float y1 = fminf(fmaxf((float)(yc - hv * 0.5), 0.f), H);
    float y2 = fminf(fmaxf((float)(yc + hv * 0.5), 0.f), H);
    boxes[(size_t)idx * 4 + 0] = x1;
    boxes[(size_t)idx * 4 + 1] = y1;
    boxes[(size_t)idx * 4 + 2] = x2;
    boxes[(size_t)idx * 4 + 3] = y2;
}

// find boundary bin B1 so that count(bins >= B1) >= 2000, count(bins > B1) < 2000
__global__ __launch_bounds__(256) void k_scanhist(const u32* __restrict__ hist, u32* __restrict__ misc) {
    __shared__ u32 csum[256];
    __shared__ u32 cb[256];
    __shared__ int s_cidx;
    __shared__ u32 s_cacc;
    int t = threadIdx.x;
    u32 sum = 0;
    const uint4* h4 = (const uint4*)(hist + t * 256);
    for (int j = 0; j < 64; j++) { uint4 v = h4[j]; sum += v.x + v.y + v.z + v.w; }
    csum[t] = sum;
    __syncthreads();
    if (t == 0) {
        u32 acc = 0;
        int c = 255;
        for (; c > 0; c--) {
            if (acc + csum[c] >= NKEEP) break;
            acc += csum[c];
        }
        s_cidx = c;
        s_cacc = acc;
    }
    __syncthreads();
    cb[t] = hist[s_cidx * 256 + t];
    __syncthreads();
    if (t == 0) {
        u32 acc = s_cacc;
        int b = 255;
        for (; b > 0; b--) {
            acc += cb[b];
            if (acc >= NKEEP) break;
        }
        misc[1] = (u32)(s_cidx * 256 + b);
    }
}

__global__ __launch_bounds__(256) void k_compact(const float* __restrict__ scores, u32* __restrict__ misc,
                                                 u64* __restrict__ keys) {
    int idx = blockIdx.x * 256 + threadIdx.x;
    if (idx >= A_TOTAL) return;
    u32 bits = __float_as_uint(scores[idx]);
    if ((bits >> 16) >= misc[1]) {
        u32 slot = atomicAdd(&misc[0], 1u);
        if (slot < SORTN) keys[slot] = ((u64)bits << 32) | (u64)(~(u32)idx);
    }
}

// bitonic sort 4096 keys DESC (score desc, index asc), then gather cand rows + init suppression words
__global__ __launch_bounds__(1024) void k_sort(const u64* __restrict__ keys, const float* __restrict__ boxes,
                                               float* __restrict__ cand5, u64* __restrict__ suppws) {
    __shared__ u64 lk[SORTN];
    int t = threadIdx.x;
#pragma unroll
    for (int r = 0; r < 4; r++) lk[r * 1024 + t] = keys[r * 1024 + t];
    for (int kk = 2; kk <= SORTN; kk <<= 1) {
        for (int jj = kk >> 1; jj > 0; jj >>= 1) {
            __syncthreads();
#pragma unroll
            for (int rep = 0; rep < 4; rep++) {
                int i = rep * 1024 + t;
                int ixj = i ^ jj;
                if (ixj > i) {
                    u64 a = lk[i], b = lk[ixj];
                    bool sw = ((i & kk) == 0) ? (a < b) : (a > b);  // descending overall
                    if (sw) { lk[i] = b; lk[ixj] = a; }
                }
            }
        }
    }
    __syncthreads();
#pragma unroll
    for (int rep = 0; rep < 2; rep++) {
        int i = rep * 1024 + t;
        bool suppb = true;
        float c0 = 0.f, c1 = 0.f, c2 = 0.f, c3 = 0.f, cs = 0.f;
        if (i < NKEEP) {
            u64 key = lk[i];
            u32 idx = ~(u32)(key & 0xFFFFFFFFull);
            cs = __uint_as_float((u32)(key >> 32));
            c0 = boxes[(size_t)idx * 4 + 0];
            c1 = boxes[(size_t)idx * 4 + 1];
            c2 = boxes[(size_t)idx * 4 + 2];
            c3 = boxes[(size_t)idx * 4 + 3];
            bool valid = ((c2 - c0) >= 16.f) && ((c3 - c1) >= 16.f) && (cs >= 0.05f);
            suppb = !valid;
        }
        cand5[i * 5 + 0] = c0;
        cand5[i * 5 + 1] = c1;
        cand5[i * 5 + 2] = c2;
        cand5[i * 5 + 3] = c3;
        cand5[i * 5 + 4] = cs;
        u64 bal = __ballot(suppb ? 1 : 0);
        if ((t & 63) == 0) suppws[i >> 6] = bal;
    }
}

// IoU > 0.7 bitmask, 64x64 tiles
__global__ __launch_bounds__(64) void k_mask(const float* __restrict__ cand5, u64* __restrict__ mask) {
    __shared__ float cb[64][5];
    int t = threadIdx.x;
    int bi = blockIdx.y, bj = blockIdx.x;
    int j = bj * 64 + t;
    {
        float b0 = cand5[j * 5 + 0], b1v = cand5[j * 5 + 1], b2v = cand5[j * 5 + 2], b3v = cand5[j * 5 + 3];
        cb[t][0] = b0; cb[t][1] = b1v; cb[t][2] = b2v; cb[t][3] = b3v;
        cb[t][4] = (b2v - b0) * (b3v - b1v);
    }
    __syncthreads();
    int i = bi * 64 + t;
    float r0 = cand5[i * 5 + 0], r1 = cand5[i * 5 + 1], r2 = cand5[i * 5 + 2], r3 = cand5[i * 5 + 3];
    float ra = (r2 - r0) * (r3 - r1);
    u64 bits = 0ull;
#pragma unroll 4
    for (int c = 0; c < 64; c++) {
        float lx = fmaxf(r0, cb[c][0]);
        float ly = fmaxf(r1, cb[c][1]);
        float rx = fminf(r2, cb[c][2]);
        float ry = fminf(r3, cb[c][3]);
        float w = fmaxf(rx - lx, 0.f);
        float h = fmaxf(ry - ly, 0.f);
        float inter = w * h;
        float iou = inter / fmaxf(ra + cb[c][4] - inter, 1e-6f);
        if (iou > 0.7f) bits |= (1ull << c);
    }
    mask[(size_t)i * 32 + bj] = bits;
}

// single-wave greedy NMS scan with depth-8 prefetch; writes first <=300 kept rows
__global__ __launch_bounds__(64) void k_scan(const u64* __restrict__ mask, const float* __restrict__ cand5,
                                             const u64* __restrict__ suppws, float* __restrict__ out) {
    int lane = threadIdx.x;
    u64 supp = (lane < 32) ? suppws[lane] : 0ull;
    u64 bufA[8], bufB[8];
    float dA[8], dB[8];
#pragma unroll
    for (int k = 0; k < 8; k++) {
        bufA[k] = (lane < 32) ? mask[(size_t)k * 32 + lane] : 0ull;
        dA[k] = (lane < 5) ? cand5[k * 5 + lane] : 0.f;
    }
    int kcount = 0;
    for (int g = 0; g < 256; g++) {
        int base = g * 8;
        if (g < 255) {
            int nb = base + 8;
#pragma unroll
            for (int k = 0; k < 8; k++) {
                bufB[k] = (lane < 32) ? mask[(size_t)(nb + k) * 32 + lane] : 0ull;
                dB[k] = (lane < 5) ? cand5[(nb + k) * 5 + lane] : 0.f;
            }
        }
        int w = g >> 3;
        u64 cur = __shfl(supp, w);
#pragma unroll
        for (int k = 0; k < 8; k++) {
            int i = base + k;
            if (i < NKEEP && !((cur >> (i & 63)) & 1ull)) {
                if (kcount < NTOPK) {
                    if (lane < 5) out[kcount * 5 + lane] = dA[k];
                    kcount++;
                }
                supp |= bufA[k];
                cur |= __shfl(bufA[k], w);
            }
        }
        if (kcount >= NTOPK) return;
#pragma unroll
        for (int k = 0; k < 8; k++) { bufA[k] = bufB[k]; dA[k] = dB[k]; }
    }
}

extern "C" void kernel_launch(void* const* d_in, const int* in_sizes, int n_in,
                              void* d_out, int out_size, void* d_ws, size_t ws_size,
                              hipStream_t stream) {
    (void)in_sizes; (void)n_in; (void)out_size; (void)ws_size;
    const float* fx = (const float*)d_in[0];
    const float* w1 = (const float*)d_in[1];
    const float* b1 = (const float*)d_in[2];
    const float* w2 = (const float*)d_in[3];
    const float* b2 = (const float*)d_in[4];
    const float* w3 = (const float*)d_in[5];
    const float* b3 = (const float*)d_in[6];
    const int* imh = (const int*)d_in[7];
    const int* imw = (const int*)d_in[8];

    char* ws = (char*)d_ws;
    float* x      = (float*)(ws + OFF_X);
    float* ox     = (float*)(ws + OFF_OX);
    float* ax3    = (float*)(ws + OFF_AX);
    float* boxes  = (float*)(ws + OFF_BOXES);
    float* scores = (float*)(ws + OFF_SCORES);
    u32*   hist   = (u32*)(ws + OFF_HIST);
    u64*   keys   = (u64*)(ws + OFF_KEYS);
    float* cand5  = (float*)(ws + OFF_CAND5);
    u64*   mask   = (u64*)(ws + OFF_MASK);
    u32*   misc   = (u32*)(ws + OFF_MISC);
    u64*   suppws = (u64*)(ws + OFF_MISC + 64);
    float* out    = (float*)d_out;

    k_init<<<256, 256, 0, stream>>>(hist, keys, misc, out);
    k_conv1<<<dim3(8, 64), 256, 0, stream>>>(fx, w1, b1, x);
    k_conv23<<<960, 256, 0, stream>>>(x, w2, b2, w3, b3, ox, ax3);
    k_boxes<<<192, 256, 0, stream>>>(ox, ax3, imh, imw, boxes, scores, hist);
    k_scanhist<<<1, 256, 0, stream>>>(hist, misc);
    k_compact<<<192, 256, 0, stream>>>(scores, misc, keys);
    k_sort<<<1, 1024, 0, stream>>>(keys, boxes, cand5, suppws);
    k_mask<<<dim3(32, 32), 64, 0, stream>>>(cand5, mask);
    k_scan<<<1, 64, 0, stream>>>(mask, cand5, suppws, out);
}